// Round 1
// baseline (682.213 us; speedup 1.0000x reference)
//
#include <hip/hip_runtime.h>

typedef __attribute__((ext_vector_type(8))) short bf16x8;
typedef __attribute__((ext_vector_type(4))) float f32x4;

#define MSTRIDE 264   // Rb/Ob row stride in shorts (528B, 16B aligned, bank-balanced)
#define XSTRIDE 392   // Xs row stride in shorts (784B, 16B aligned, bank-balanced)

// Pre-converted transposed weights (bf16, [n][k]) — module-scope device memory,
// rewritten every call by transcvt. L2-resident (640 KB total).
__device__ __align__(16) unsigned short g_WQT[256 * 256];
__device__ __align__(16) unsigned short g_WKVT[512 * 384];
__device__ __align__(16) unsigned short g_WOT[256 * 256];

__device__ __forceinline__ float b2f(unsigned short u) {
    union { unsigned int i; float f; } v; v.i = ((unsigned int)u) << 16; return v.f;
}
__device__ __forceinline__ unsigned short f2b(float f) {
    union { float f; unsigned int i; } v; v.f = f;
    unsigned int x = v.i;
    return (unsigned short)((x + 0x7fffu + ((x >> 16) & 1u)) >> 16);  // RNE
}

// dst[c][r] = bf16(src[r][c]) — f32 [R][C] -> bf16 [C][R]; dims multiples of 32.
__global__ void transcvt(const float* __restrict__ src, unsigned short* __restrict__ dst,
                         int R, int C) {
    __shared__ float tile[32][33];
    const int c0 = blockIdx.x * 32, r0 = blockIdx.y * 32;
    const int tx = threadIdx.x, ty = threadIdx.y;   // 32 x 8
#pragma unroll
    for (int i = 0; i < 32; i += 8)
        tile[ty + i][tx] = src[(size_t)(r0 + ty + i) * C + (c0 + tx)];
    __syncthreads();
#pragma unroll
    for (int i = 0; i < 32; i += 8)
        dst[(size_t)(c0 + ty + i) * R + (r0 + tx)] = f2b(tile[tx][ty + i]);
}

// load 8 consecutive f32, convert, store 8 bf16 (16B) to LDS
__device__ __forceinline__ void ld8f(const float* __restrict__ s, unsigned short* dst) {
    const float4 a = *(const float4*)s;
    const float4 b = *(const float4*)(s + 4);
    unsigned short t[8];
    t[0] = f2b(a.x); t[1] = f2b(a.y); t[2] = f2b(a.z); t[3] = f2b(a.w);
    t[4] = f2b(b.x); t[5] = f2b(b.y); t[6] = f2b(b.z); t[7] = f2b(b.w);
    *(uint4*)dst = *(const uint4*)t;
}

// Fully fused temporal attention: one WG = 2 batch elements, 4 waves.
// Wave w owns heads {2w, 2w+1} (cols [64w, 64w+64) of the K-half / V-half).
// v2: barrier-free K-loops — B-fragments loaded DIRECTLY global->reg from the
// L2-resident transposed weights (each wave reads only its own 128 rows, so
// there is nothing to share via LDS); X is converted/staged to LDS ONCE for
// all 12 k-chunks. Workgroup barriers: 3 total (was 56).
__global__ __launch_bounds__(256, 2) void ta_fused(
    const float* __restrict__ node,
    const float* __restrict__ timef,
    const float* __restrict__ edge,
    const float* __restrict__ nbrnode,
    const float* __restrict__ nbrtime,
    const int* __restrict__ nmask,
    const float* __restrict__ bO,
    const float* __restrict__ gam,
    const float* __restrict__ bet,
    float* __restrict__ out)
{
    __shared__ __align__(16) unsigned short Xs[64 * XSTRIDE];   // 49 KB  X bf16 [row][k]
    __shared__ __align__(16) unsigned short Rb[16 * MSTRIDE];   // residual R, padded to M=16
    __shared__ __align__(16) unsigned short Ob[16 * MSTRIDE];   // attention out O, padded to M=16
    __shared__ float lnb[2][256];
    __shared__ int   mk[2][32];

    const int gb0  = blockIdx.x * 2;
    const int tid  = threadIdx.x;
    const int w    = tid >> 6;
    const int lane = tid & 63;
    const int l15  = lane & 15;
    const int quad = lane >> 4;

    // mask stride sniff: int64 masks read as int32 have all odd words == 0
    bool m64 = true;
    for (int i = 1; i < 64; i += 2) m64 = m64 && (nmask[i] == 0);

    // ---- init: zero Ob fully, zero Rb rows 2..15 (rows 0,1 loaded below) ----
    {
        unsigned int* pO = (unsigned int*)Ob;
        for (int i = tid; i < 16 * MSTRIDE / 2; i += 256) pO[i] = 0u;
        unsigned int* pR = (unsigned int*)Rb;
        for (int i = tid + MSTRIDE; i < 16 * MSTRIDE / 2; i += 256) pR[i] = 0u;
    }
    if (tid < 64) {               // R rows: concat(node, time) for b=0,1
        const int b = tid >> 5, s = tid & 31;
        if (s < 16) ld8f(node  + (size_t)(gb0 + b) * 128 + s * 8,        &Rb[b * MSTRIDE + s * 8]);
        else        ld8f(timef + (size_t)(gb0 + b) * 128 + (s - 16) * 8, &Rb[b * MSTRIDE + s * 8]);
    } else if (tid < 128) {       // neighbor masks
        const int t = tid - 64, b = t >> 5, n = t & 31;
        const size_t j = (size_t)(gb0 + b) * 32 + n;
        mk[b][n] = m64 ? nmask[2 * j] : nmask[j];
    }
    // ---- stage X = concat(nbr_node, edge, nbr_time) bf16 [64][384], once ----
#pragma unroll
    for (int i = 0; i < 12; i++) {
        const int g  = i * 256 + tid;        // 0..3071
        const int r  = g / 48, c8 = g % 48;  // row 0..63, 8-elem chunk 0..47
        const float* base; int koff;
        if (c8 < 16)      { base = nbrnode; koff = c8 * 8; }
        else if (c8 < 32) { base = edge;    koff = (c8 - 16) * 8; }
        else              { base = nbrtime; koff = (c8 - 32) * 8; }
        ld8f(base + (size_t)(gb0 * 32 + r) * 128 + koff, &Xs[r * XSTRIDE + c8 * 8]);
    }
    __syncthreads();   // barrier #1: Rb/Xs/mk/Ob-zero visible to all waves

    const f32x4 zero4 = {0.0f, 0.0f, 0.0f, 0.0f};

    // ================= Phase 0: Q = R @ W_Q  (M=16 padded, rows 0,1 real) =================
    // B-fragments direct from global (L2): n = w*64 + ct*16 + l15, k = kc*32 + quad*8
    f32x4 accq[4];
#pragma unroll
    for (int ct = 0; ct < 4; ct++) accq[ct] = zero4;
    {
        const unsigned short* wq = g_WQT + (size_t)(w * 64 + l15) * 256 + quad * 8;
#pragma unroll 2
        for (int kc = 0; kc < 8; kc++) {
            const bf16x8 afr = *(const bf16x8*)(&Rb[l15 * MSTRIDE + kc * 32 + quad * 8]);
#pragma unroll
            for (int ct = 0; ct < 4; ct++) {
                const bf16x8 b = *(const bf16x8*)(wq + (size_t)(ct * 16) * 256 + kc * 32);
                accq[ct] = __builtin_amdgcn_mfma_f32_16x16x32_bf16(afr, b, accq[ct], 0, 0, 0);
            }
        }
    }
    // Q rows 0,1 live in quad==0 lanes, regs accq[ct][0..1]; broadcast later via shfl.

    // ============ Phase 1: K,V = X @ W_KV  fused (64 x 256 each, K=384) ============
    f32x4 accK[4][4], accV[4][4];
#pragma unroll
    for (int rt = 0; rt < 4; rt++)
#pragma unroll
        for (int ct = 0; ct < 4; ct++) { accK[rt][ct] = zero4; accV[rt][ct] = zero4; }
    {
        const unsigned short* wkv = g_WKVT + (size_t)(w * 64 + l15) * 384 + quad * 8;
#pragma unroll 2
        for (int kc = 0; kc < 12; kc++) {
            bf16x8 af[4];
#pragma unroll
            for (int rt = 0; rt < 4; rt++)
                af[rt] = *(const bf16x8*)(&Xs[(rt * 16 + l15) * XSTRIDE + kc * 32 + quad * 8]);
            bf16x8 bK[4], bV[4];
#pragma unroll
            for (int ct = 0; ct < 4; ct++) {
                bK[ct] = *(const bf16x8*)(wkv + (size_t)(ct * 16) * 384 + kc * 32);
                bV[ct] = *(const bf16x8*)(wkv + (size_t)(256 + ct * 16) * 384 + kc * 32);
            }
            __builtin_amdgcn_s_setprio(1);
#pragma unroll
            for (int ct = 0; ct < 4; ct++)
#pragma unroll
                for (int rt = 0; rt < 4; rt++) {
                    accK[rt][ct] = __builtin_amdgcn_mfma_f32_16x16x32_bf16(af[rt], bK[ct], accK[rt][ct], 0, 0, 0);
                    accV[rt][ct] = __builtin_amdgcn_mfma_f32_16x16x32_bf16(af[rt], bV[ct], accV[rt][ct], 0, 0, 0);
                }
            __builtin_amdgcn_s_setprio(0);
        }
    }

    // ================= Phase 2: scores + masked softmax (all in C-layout) =================
    // accK: lane holds K[row n = rt*16+quad*4+rg][dcol = 64w+ct*16+l15].
    float aw[2][2][2][4];
    const float scl = 0.17677669529663687f;   // 32^-0.5
#pragma unroll
    for (int bb = 0; bb < 2; bb++) {
        float qv[4];
#pragma unroll
        for (int ct = 0; ct < 4; ct++) qv[ct] = __shfl(accq[ct][bb], l15, 64);
#pragma unroll
        for (int hl = 0; hl < 2; hl++) {
            float sv[2][4];
#pragma unroll
            for (int rtl = 0; rtl < 2; rtl++) {
                const int rt = bb * 2 + rtl;
#pragma unroll
                for (int rg = 0; rg < 4; rg++)
                    sv[rtl][rg] = accK[rt][2 * hl][rg] * qv[2 * hl]
                                + accK[rt][2 * hl + 1][rg] * qv[2 * hl + 1];
            }
#pragma unroll
            for (int m = 1; m <= 8; m <<= 1)
#pragma unroll
                for (int rtl = 0; rtl < 2; rtl++)
#pragma unroll
                    for (int rg = 0; rg < 4; rg++)
                        sv[rtl][rg] += __shfl_xor(sv[rtl][rg], m, 64);
            float mx = -3.0e38f;
#pragma unroll
            for (int rtl = 0; rtl < 2; rtl++)
#pragma unroll
                for (int rg = 0; rg < 4; rg++) {
                    const int n = rtl * 16 + quad * 4 + rg;
                    sv[rtl][rg] = (mk[bb][n] != 0) ? sv[rtl][rg] * scl : -1.0e10f;
                    mx = fmaxf(mx, sv[rtl][rg]);
                }
            mx = fmaxf(mx, __shfl_xor(mx, 16, 64));
            mx = fmaxf(mx, __shfl_xor(mx, 32, 64));
            float sum = 0.0f;
#pragma unroll
            for (int rtl = 0; rtl < 2; rtl++)
#pragma unroll
                for (int rg = 0; rg < 4; rg++) {
                    const float e = __expf(sv[rtl][rg] - mx);
                    aw[bb][hl][rtl][rg] = e;
                    sum += e;
                }
            sum += __shfl_xor(sum, 16, 64);
            sum += __shfl_xor(sum, 32, 64);
            const float inv = 1.0f / sum;
#pragma unroll
            for (int rtl = 0; rtl < 2; rtl++)
#pragma unroll
                for (int rg = 0; rg < 4; rg++)
                    aw[bb][hl][rtl][rg] *= inv;
        }
    }

    // ================= Phase 3: O = A @ V  (reduce over rows n -> quad shuffles) =========
#pragma unroll
    for (int bb = 0; bb < 2; bb++)
#pragma unroll
        for (int hl = 0; hl < 2; hl++)
#pragma unroll
            for (int ctl = 0; ctl < 2; ctl++) {
                const int ct = hl * 2 + ctl;
                float o = 0.0f;
#pragma unroll
                for (int rtl = 0; rtl < 2; rtl++)
#pragma unroll
                    for (int rg = 0; rg < 4; rg++)
                        o += aw[bb][hl][rtl][rg] * accV[bb * 2 + rtl][ct][rg];
                o += __shfl_xor(o, 16, 64);
                o += __shfl_xor(o, 32, 64);
                if (quad == 0) {
                    const int col = (w * 2 + hl) * 32 + ctl * 16 + l15;
                    Ob[bb * MSTRIDE + col] = f2b(o);
                }
            }
    __syncthreads();   // barrier #2: all waves' O columns visible

    // ================= Phase 4: out = O @ W_O + b_O + R, then LayerNorm =================
    f32x4 acco[4];
#pragma unroll
    for (int ct = 0; ct < 4; ct++) acco[ct] = zero4;
    {
        const unsigned short* wo = g_WOT + (size_t)(w * 64 + l15) * 256 + quad * 8;
#pragma unroll 2
        for (int kc = 0; kc < 8; kc++) {
            const bf16x8 afr = *(const bf16x8*)(&Ob[l15 * MSTRIDE + kc * 32 + quad * 8]);
#pragma unroll
            for (int ct = 0; ct < 4; ct++) {
                const bf16x8 b = *(const bf16x8*)(wo + (size_t)(ct * 16) * 256 + kc * 32);
                acco[ct] = __builtin_amdgcn_mfma_f32_16x16x32_bf16(afr, b, acco[ct], 0, 0, 0);
            }
        }
    }
    if (quad == 0) {
#pragma unroll
        for (int ct = 0; ct < 4; ct++) {
#pragma unroll
            for (int r = 0; r < 2; r++) {
                const int col = w * 64 + ct * 16 + l15;
                lnb[r][col] = acco[ct][r] + bO[col] + b2f(Rb[r * MSTRIDE + col]);
            }
        }
    }
    __syncthreads();   // barrier #3: lnb complete

    if (w < 2) {   // wave 0 -> batch 0, wave 1 -> batch 1
        const int bb = w;
        float x[4]; float s = 0.0f;
#pragma unroll
        for (int i = 0; i < 4; i++) { x[i] = lnb[bb][lane + i * 64]; s += x[i]; }
#pragma unroll
        for (int m = 1; m <= 32; m <<= 1) s += __shfl_xor(s, m, 64);
        const float mu = s * (1.0f / 256.0f);
        float s2 = 0.0f;
#pragma unroll
        for (int i = 0; i < 4; i++) { const float d = x[i] - mu; s2 += d * d; }
#pragma unroll
        for (int m = 1; m <= 32; m <<= 1) s2 += __shfl_xor(s2, m, 64);
        const float rstd = rsqrtf(s2 * (1.0f / 256.0f) + 1e-5f);
#pragma unroll
        for (int i = 0; i < 4; i++) {
            const int col = lane + i * 64;
            out[(size_t)(gb0 + bb) * 256 + col] =
                (x[i] - mu) * rstd * gam[col] + bet[col];
        }
    }
}

extern "C" void kernel_launch(void* const* d_in, const int* in_sizes, int n_in,
                              void* d_out, int out_size, void* d_ws, size_t ws_size,
                              hipStream_t stream) {
    const float* node    = (const float*)d_in[0];
    const float* timef   = (const float*)d_in[1];
    const float* edge    = (const float*)d_in[2];
    const float* nbrnode = (const float*)d_in[3];
    const float* nbrtime = (const float*)d_in[4];
    const int*   nmask   = (const int*)d_in[5];
    const float* W_Q     = (const float*)d_in[6];
    const float* W_KV    = (const float*)d_in[7];
    const float* W_O     = (const float*)d_in[8];
    const float* bO      = (const float*)d_in[9];
    const float* gam     = (const float*)d_in[10];
    const float* bet     = (const float*)d_in[11];

    unsigned short *wqt, *wkvt, *wot;
    hipGetSymbolAddress((void**)&wqt,  HIP_SYMBOL(g_WQT));
    hipGetSymbolAddress((void**)&wkvt, HIP_SYMBOL(g_WKVT));
    hipGetSymbolAddress((void**)&wot,  HIP_SYMBOL(g_WOT));

    transcvt<<<dim3(8, 8),   dim3(32, 8), 0, stream>>>(W_Q,  wqt,  256, 256);
    transcvt<<<dim3(16, 12), dim3(32, 8), 0, stream>>>(W_KV, wkvt, 384, 512);
    transcvt<<<dim3(8, 8),   dim3(32, 8), 0, stream>>>(W_O,  wot,  256, 256);

    ta_fused<<<4096, 256, 0, stream>>>(node, timef, edge, nbrnode, nbrtime, nmask,
                                       bO, gam, bet, (float*)d_out);
}

// Round 2
// 666.010 us; speedup vs baseline: 1.0243x; 1.0243x over previous
//
#include <hip/hip_runtime.h>

typedef __attribute__((ext_vector_type(8))) short bf16x8;
typedef __attribute__((ext_vector_type(4))) float f32x4;

#define MSTRIDE 264   // Rb/Ob row stride in shorts (528B, 16B aligned, bank-balanced)
#define XSTRIDE 392   // Xs row stride in shorts (784B, 16B aligned, bank-balanced)

// Pre-converted transposed weights (bf16, [n][k]) — module-scope device memory,
// rewritten every call by transcvt_all. L2-resident (640 KB total).
__device__ __align__(16) unsigned short g_WQT[256 * 256];
__device__ __align__(16) unsigned short g_WKVT[512 * 384];
__device__ __align__(16) unsigned short g_WOT[256 * 256];

__device__ __forceinline__ float b2f(unsigned short u) {
    union { unsigned int i; float f; } v; v.i = ((unsigned int)u) << 16; return v.f;
}
__device__ __forceinline__ unsigned short f2b(float f) {
    union { float f; unsigned int i; } v; v.f = f;
    unsigned int x = v.i;
    return (unsigned short)((x + 0x7fffu + ((x >> 16) & 1u)) >> 16);  // RNE
}

// One launch transposes+converts all three weight matrices.
// dst[c][r] = bf16(src[r][c]); tiles flattened into blockIdx.x.
__global__ void transcvt_all(const float* __restrict__ wq, const float* __restrict__ wkv,
                             const float* __restrict__ wo,
                             unsigned short* __restrict__ dq, unsigned short* __restrict__ dkv,
                             unsigned short* __restrict__ dwo) {
    __shared__ float tile[32][33];
    const int b = blockIdx.x;
    const float* src; unsigned short* dst; int R, C, bx, by;
    if (b < 64)       { src = wq;  dst = dq;  R = 256; C = 256; bx = b & 7;  by = b >> 3; }
    else if (b < 256) { const int t = b - 64;  src = wkv; dst = dkv; R = 384; C = 512; bx = t & 15; by = t >> 4; }
    else              { const int t = b - 256; src = wo;  dst = dwo; R = 256; C = 256; bx = t & 7;  by = t >> 3; }
    const int c0 = bx * 32, r0 = by * 32;
    const int tx = threadIdx.x, ty = threadIdx.y;   // 32 x 8
#pragma unroll
    for (int i = 0; i < 32; i += 8)
        tile[ty + i][tx] = src[(size_t)(r0 + ty + i) * C + (c0 + tx)];
    __syncthreads();
#pragma unroll
    for (int i = 0; i < 32; i += 8)
        dst[(size_t)(c0 + ty + i) * R + (r0 + tx)] = f2b(tile[tx][ty + i]);
}

// load 8 consecutive f32, convert, store 8 bf16 (16B) to LDS
__device__ __forceinline__ void ld8f(const float* __restrict__ s, unsigned short* dst) {
    const float4 a = *(const float4*)s;
    const float4 b = *(const float4*)(s + 4);
    unsigned short t[8];
    t[0] = f2b(a.x); t[1] = f2b(a.y); t[2] = f2b(a.z); t[3] = f2b(a.w);
    t[4] = f2b(b.x); t[5] = f2b(b.y); t[6] = f2b(b.z); t[7] = f2b(b.w);
    *(uint4*)dst = *(const uint4*)t;
}

// Fully fused temporal attention: one WG = 2 batch elements, 4 waves.
// Wave w owns heads {2w, 2w+1} (cols [64w, 64w+64) of the K-half / V-half).
// v3: latency-bound fixes — parallel mask sniff (no serial s_load chain),
// 2-set register rotation in all K-loops (loads for kc+2 issued behind the
// MFMA cluster of kc), cross-phase weight prefetch, Q spilled to LDS after
// phase 0 to keep phase-1 register peak under the 2-wave/SIMD budget.
__global__ __launch_bounds__(256, 2) void ta_fused(
    const float* __restrict__ node,
    const float* __restrict__ timef,
    const float* __restrict__ edge,
    const float* __restrict__ nbrnode,
    const float* __restrict__ nbrtime,
    const int* __restrict__ nmask,
    const float* __restrict__ bO,
    const float* __restrict__ gam,
    const float* __restrict__ bet,
    float* __restrict__ out)
{
    __shared__ __align__(16) unsigned short Xs[64 * XSTRIDE];   // 49 KB  X bf16 [row][k]
    __shared__ __align__(16) unsigned short Rb[16 * MSTRIDE];   // residual R, padded to M=16
    __shared__ __align__(16) unsigned short Ob[16 * MSTRIDE];   // attention out O, padded to M=16
    __shared__ float Qs[2][256];
    __shared__ float lnb[2][256];
    __shared__ int   mk[2][32];

    const int gb0  = blockIdx.x * 2;
    const int tid  = threadIdx.x;
    const int w    = tid >> 6;
    const int lane = tid & 63;
    const int l15  = lane & 15;
    const int quad = lane >> 4;

    // mask stride sniff, PARALLEL: int64 masks read as int32 have all odd words == 0.
    // bitwise OR accumulate -> all 32 loads independent, single wait (was a serial
    // short-circuit chain of dependent scalar loads).
    int orv = 0;
#pragma unroll
    for (int i = 1; i < 64; i += 2) orv |= nmask[i];
    const bool m64 = (orv == 0);

    // ---- init: zero Ob fully, zero Rb rows 2..15 (rows 0,1 loaded below) ----
    {
        unsigned int* pO = (unsigned int*)Ob;
        for (int i = tid; i < 16 * MSTRIDE / 2; i += 256) pO[i] = 0u;
        unsigned int* pR = (unsigned int*)Rb;
        for (int i = tid + MSTRIDE; i < 16 * MSTRIDE / 2; i += 256) pR[i] = 0u;
    }
    if (tid < 64) {               // R rows: concat(node, time) for b=0,1
        const int b = tid >> 5, s = tid & 31;
        if (s < 16) ld8f(node  + (size_t)(gb0 + b) * 128 + s * 8,        &Rb[b * MSTRIDE + s * 8]);
        else        ld8f(timef + (size_t)(gb0 + b) * 128 + (s - 16) * 8, &Rb[b * MSTRIDE + s * 8]);
    } else if (tid < 128) {       // neighbor masks
        const int t = tid - 64, b = t >> 5, n = t & 31;
        const size_t j = (size_t)(gb0 + b) * 32 + n;
        mk[b][n] = m64 ? nmask[2 * j] : nmask[j];
    }
    // ---- stage X = concat(nbr_node, edge, nbr_time) bf16 [64][384], once ----
#pragma unroll
    for (int i = 0; i < 12; i++) {
        const int g  = i * 256 + tid;        // 0..3071
        const int r  = g / 48, c8 = g % 48;  // row 0..63, 8-elem chunk 0..47
        const float* base; int koff;
        if (c8 < 16)      { base = nbrnode; koff = c8 * 8; }
        else if (c8 < 32) { base = edge;    koff = (c8 - 16) * 8; }
        else              { base = nbrtime; koff = (c8 - 32) * 8; }
        ld8f(base + (size_t)(gb0 * 32 + r) * 128 + koff, &Xs[r * XSTRIDE + c8 * 8]);
    }

    // ---- pre-barrier weight prefetch (independent of LDS) ----
    const unsigned short* wq  = g_WQT  + (size_t)(w * 64 + l15) * 256 + quad * 8;
    const unsigned short* wkv = g_WKVT + (size_t)(w * 64 + l15) * 384 + quad * 8;
    const unsigned short* wo  = g_WOT  + (size_t)(w * 64 + l15) * 256 + quad * 8;
    bf16x8 bq[2][4], bK[2][4], bV[2][4];
#pragma unroll
    for (int p = 0; p < 2; p++)
#pragma unroll
        for (int ct = 0; ct < 4; ct++)
            bq[p][ct] = *(const bf16x8*)(wq + (size_t)(ct * 16) * 256 + p * 32);
#pragma unroll
    for (int ct = 0; ct < 4; ct++) {
        bK[0][ct] = *(const bf16x8*)(wkv + (size_t)(ct * 16) * 384);
        bV[0][ct] = *(const bf16x8*)(wkv + (size_t)(256 + ct * 16) * 384);
    }

    __syncthreads();   // barrier #1: Rb/Xs/mk/Ob-zero visible to all waves

    const f32x4 zero4 = {0.0f, 0.0f, 0.0f, 0.0f};

    // ================= Phase 0: Q = R @ W_Q (rotated: loads for kc+2 behind MFMA kc) =====
    f32x4 accq[4];
#pragma unroll
    for (int ct = 0; ct < 4; ct++) accq[ct] = zero4;
    {
        bf16x8 aq[2];
        aq[0] = *(const bf16x8*)(&Rb[l15 * MSTRIDE + 0 * 32 + quad * 8]);
        aq[1] = *(const bf16x8*)(&Rb[l15 * MSTRIDE + 1 * 32 + quad * 8]);
#pragma unroll
        for (int kc = 0; kc < 8; kc++) {
            const int s = kc & 1;
#pragma unroll
            for (int ct = 0; ct < 4; ct++)
                accq[ct] = __builtin_amdgcn_mfma_f32_16x16x32_bf16(aq[s], bq[s][ct], accq[ct], 0, 0, 0);
            if (kc + 2 < 8) {
                aq[s] = *(const bf16x8*)(&Rb[l15 * MSTRIDE + (kc + 2) * 32 + quad * 8]);
#pragma unroll
                for (int ct = 0; ct < 4; ct++)
                    bq[s][ct] = *(const bf16x8*)(wq + (size_t)(ct * 16) * 256 + (kc + 2) * 32);
            }
        }
    }
    if (quad == 0) {  // park Q in LDS; frees accq AGPRs for phase 1
#pragma unroll
        for (int ct = 0; ct < 4; ct++) {
            Qs[0][w * 64 + ct * 16 + l15] = accq[ct][0];
            Qs[1][w * 64 + ct * 16 + l15] = accq[ct][1];
        }
    }

    // ============ Phase 1: K,V = X @ W_KV fused, 2-set rotation on af/bK/bV ============
    f32x4 accK[4][4], accV[4][4];
#pragma unroll
    for (int rt = 0; rt < 4; rt++)
#pragma unroll
        for (int ct = 0; ct < 4; ct++) { accK[rt][ct] = zero4; accV[rt][ct] = zero4; }
    {
        bf16x8 af[2][4];
#pragma unroll
        for (int rt = 0; rt < 4; rt++)
            af[0][rt] = *(const bf16x8*)(&Xs[(rt * 16 + l15) * XSTRIDE + quad * 8]);
#pragma unroll
        for (int ct = 0; ct < 4; ct++) {
            bK[1][ct] = *(const bf16x8*)(wkv + (size_t)(ct * 16) * 384 + 32);
            bV[1][ct] = *(const bf16x8*)(wkv + (size_t)(256 + ct * 16) * 384 + 32);
        }
#pragma unroll
        for (int kc = 0; kc < 12; kc++) {
            const int s = kc & 1;
            if (kc + 1 < 12) {   // af for kc+1 issued ahead of this cluster
#pragma unroll
                for (int rt = 0; rt < 4; rt++)
                    af[s ^ 1][rt] = *(const bf16x8*)(&Xs[(rt * 16 + l15) * XSTRIDE + (kc + 1) * 32 + quad * 8]);
            }
            __builtin_amdgcn_s_setprio(1);
#pragma unroll
            for (int ct = 0; ct < 4; ct++)
#pragma unroll
                for (int rt = 0; rt < 4; rt++) {
                    accK[rt][ct] = __builtin_amdgcn_mfma_f32_16x16x32_bf16(af[s][rt], bK[s][ct], accK[rt][ct], 0, 0, 0);
                    accV[rt][ct] = __builtin_amdgcn_mfma_f32_16x16x32_bf16(af[s][rt], bV[s][ct], accV[rt][ct], 0, 0, 0);
                }
            __builtin_amdgcn_s_setprio(0);
            if (kc + 2 < 12) {   // weights for kc+2 issued behind this cluster
#pragma unroll
                for (int ct = 0; ct < 4; ct++) {
                    bK[s][ct] = *(const bf16x8*)(wkv + (size_t)(ct * 16) * 384 + (kc + 2) * 32);
                    bV[s][ct] = *(const bf16x8*)(wkv + (size_t)(256 + ct * 16) * 384 + (kc + 2) * 32);
                }
            }
        }
    }

    // prefetch W_O kc=0,1 — completes under softmax/PV
    bf16x8 bo[2][4];
#pragma unroll
    for (int p = 0; p < 2; p++)
#pragma unroll
        for (int ct = 0; ct < 4; ct++)
            bo[p][ct] = *(const bf16x8*)(wo + (size_t)(ct * 16) * 256 + p * 32);

    // ================= Phase 2: scores + masked softmax (all in C-layout) =================
    // accK: lane holds K[row n = rt*16+quad*4+rg][dcol = 64w+ct*16+l15].
    float aw[2][2][2][4];
    const float scl = 0.17677669529663687f;   // 32^-0.5
#pragma unroll
    for (int bb = 0; bb < 2; bb++) {
        float qv[4];
#pragma unroll
        for (int ct = 0; ct < 4; ct++) qv[ct] = Qs[bb][w * 64 + ct * 16 + l15];
#pragma unroll
        for (int hl = 0; hl < 2; hl++) {
            float sv[2][4];
#pragma unroll
            for (int rtl = 0; rtl < 2; rtl++) {
                const int rt = bb * 2 + rtl;
#pragma unroll
                for (int rg = 0; rg < 4; rg++)
                    sv[rtl][rg] = accK[rt][2 * hl][rg] * qv[2 * hl]
                                + accK[rt][2 * hl + 1][rg] * qv[2 * hl + 1];
            }
#pragma unroll
            for (int m = 1; m <= 8; m <<= 1)
#pragma unroll
                for (int rtl = 0; rtl < 2; rtl++)
#pragma unroll
                    for (int rg = 0; rg < 4; rg++)
                        sv[rtl][rg] += __shfl_xor(sv[rtl][rg], m, 64);
            float mx = -3.0e38f;
#pragma unroll
            for (int rtl = 0; rtl < 2; rtl++)
#pragma unroll
                for (int rg = 0; rg < 4; rg++) {
                    const int n = rtl * 16 + quad * 4 + rg;
                    sv[rtl][rg] = (mk[bb][n] != 0) ? sv[rtl][rg] * scl : -1.0e10f;
                    mx = fmaxf(mx, sv[rtl][rg]);
                }
            mx = fmaxf(mx, __shfl_xor(mx, 16, 64));
            mx = fmaxf(mx, __shfl_xor(mx, 32, 64));
            float sum = 0.0f;
#pragma unroll
            for (int rtl = 0; rtl < 2; rtl++)
#pragma unroll
                for (int rg = 0; rg < 4; rg++) {
                    const float e = __expf(sv[rtl][rg] - mx);
                    aw[bb][hl][rtl][rg] = e;
                    sum += e;
                }
            sum += __shfl_xor(sum, 16, 64);
            sum += __shfl_xor(sum, 32, 64);
            const float inv = 1.0f / sum;
#pragma unroll
            for (int rtl = 0; rtl < 2; rtl++)
#pragma unroll
                for (int rg = 0; rg < 4; rg++)
                    aw[bb][hl][rtl][rg] *= inv;
        }
    }

    // ================= Phase 3: O = A @ V  (reduce over rows n -> quad shuffles) =========
#pragma unroll
    for (int bb = 0; bb < 2; bb++)
#pragma unroll
        for (int hl = 0; hl < 2; hl++)
#pragma unroll
            for (int ctl = 0; ctl < 2; ctl++) {
                const int ct = hl * 2 + ctl;
                float o = 0.0f;
#pragma unroll
                for (int rtl = 0; rtl < 2; rtl++)
#pragma unroll
                    for (int rg = 0; rg < 4; rg++)
                        o += aw[bb][hl][rtl][rg] * accV[bb * 2 + rtl][ct][rg];
                o += __shfl_xor(o, 16, 64);
                o += __shfl_xor(o, 32, 64);
                if (quad == 0) {
                    const int col = (w * 2 + hl) * 32 + ctl * 16 + l15;
                    Ob[bb * MSTRIDE + col] = f2b(o);
                }
            }
    __syncthreads();   // barrier #2: all waves' O columns visible

    // ================= Phase 4: out = O @ W_O + b_O + R, then LayerNorm =================
    f32x4 acco[4];
#pragma unroll
    for (int ct = 0; ct < 4; ct++) acco[ct] = zero4;
    {
        bf16x8 ao[2];
        ao[0] = *(const bf16x8*)(&Ob[l15 * MSTRIDE + 0 * 32 + quad * 8]);
        ao[1] = *(const bf16x8*)(&Ob[l15 * MSTRIDE + 1 * 32 + quad * 8]);
#pragma unroll
        for (int kc = 0; kc < 8; kc++) {
            const int s = kc & 1;
#pragma unroll
            for (int ct = 0; ct < 4; ct++)
                acco[ct] = __builtin_amdgcn_mfma_f32_16x16x32_bf16(ao[s], bo[s][ct], acco[ct], 0, 0, 0);
            if (kc + 2 < 8) {
                ao[s] = *(const bf16x8*)(&Ob[l15 * MSTRIDE + (kc + 2) * 32 + quad * 8]);
#pragma unroll
                for (int ct = 0; ct < 4; ct++)
                    bo[s][ct] = *(const bf16x8*)(wo + (size_t)(ct * 16) * 256 + (kc + 2) * 32);
            }
        }
    }
    if (quad == 0) {
#pragma unroll
        for (int ct = 0; ct < 4; ct++) {
#pragma unroll
            for (int r = 0; r < 2; r++) {
                const int col = w * 64 + ct * 16 + l15;
                lnb[r][col] = acco[ct][r] + bO[col] + b2f(Rb[r * MSTRIDE + col]);
            }
        }
    }
    __syncthreads();   // barrier #3: lnb complete

    if (w < 2) {   // wave 0 -> batch 0, wave 1 -> batch 1
        const int bb = w;
        float x[4]; float s = 0.0f;
#pragma unroll
        for (int i = 0; i < 4; i++) { x[i] = lnb[bb][lane + i * 64]; s += x[i]; }
#pragma unroll
        for (int m = 1; m <= 32; m <<= 1) s += __shfl_xor(s, m, 64);
        const float mu = s * (1.0f / 256.0f);
        float s2 = 0.0f;
#pragma unroll
        for (int i = 0; i < 4; i++) { const float d = x[i] - mu; s2 += d * d; }
#pragma unroll
        for (int m = 1; m <= 32; m <<= 1) s2 += __shfl_xor(s2, m, 64);
        const float rstd = rsqrtf(s2 * (1.0f / 256.0f) + 1e-5f);
#pragma unroll
        for (int i = 0; i < 4; i++) {
            const int col = lane + i * 64;
            out[(size_t)(gb0 + bb) * 256 + col] =
                (x[i] - mu) * rstd * gam[col] + bet[col];
        }
    }
}

extern "C" void kernel_launch(void* const* d_in, const int* in_sizes, int n_in,
                              void* d_out, int out_size, void* d_ws, size_t ws_size,
                              hipStream_t stream) {
    const float* node    = (const float*)d_in[0];
    const float* timef   = (const float*)d_in[1];
    const float* edge    = (const float*)d_in[2];
    const float* nbrnode = (const float*)d_in[3];
    const float* nbrtime = (const float*)d_in[4];
    const int*   nmask   = (const int*)d_in[5];
    const float* W_Q     = (const float*)d_in[6];
    const float* W_KV    = (const float*)d_in[7];
    const float* W_O     = (const float*)d_in[8];
    const float* bO      = (const float*)d_in[9];
    const float* gam     = (const float*)d_in[10];
    const float* bet     = (const float*)d_in[11];

    unsigned short *wqt, *wkvt, *wot;
    hipGetSymbolAddress((void**)&wqt,  HIP_SYMBOL(g_WQT));
    hipGetSymbolAddress((void**)&wkvt, HIP_SYMBOL(g_WKVT));
    hipGetSymbolAddress((void**)&wot,  HIP_SYMBOL(g_WOT));

    transcvt_all<<<320, dim3(32, 8), 0, stream>>>(W_Q, W_KV, W_O, wqt, wkvt, wot);

    ta_fused<<<4096, 256, 0, stream>>>(node, timef, edge, nbrnode, nbrtime, nmask,
                                       bO, gam, bet, (float*)d_out);
}

// Round 3
// 665.201 us; speedup vs baseline: 1.0256x; 1.0012x over previous
//
#include <hip/hip_runtime.h>

typedef __attribute__((ext_vector_type(8))) short bf16x8;
typedef __attribute__((ext_vector_type(4))) float f32x4;

#define MSTRIDE 264   // Rb/Ob row stride in shorts (528B, 16B aligned, bank-balanced)
#define XSTRIDE 392   // Xs row stride in shorts (784B, 16B aligned, bank-balanced)

// Pre-converted transposed weights (bf16, [n][k]) — module-scope device memory,
// rewritten every call by transcvt_all. L2-resident (640 KB total).
__device__ __align__(16) unsigned short g_WQT[256 * 256];
__device__ __align__(16) unsigned short g_WKVT[512 * 384];
__device__ __align__(16) unsigned short g_WOT[256 * 256];

__device__ __forceinline__ float b2f(unsigned short u) {
    union { unsigned int i; float f; } v; v.i = ((unsigned int)u) << 16; return v.f;
}
__device__ __forceinline__ unsigned short f2b(float f) {
    union { float f; unsigned int i; } v; v.f = f;
    unsigned int x = v.i;
    return (unsigned short)((x + 0x7fffu + ((x >> 16) & 1u)) >> 16);  // RNE
}

// One launch transposes+converts all three weight matrices.
// dst[c][r] = bf16(src[r][c]); tiles flattened into blockIdx.x.
__global__ void transcvt_all(const float* __restrict__ wq, const float* __restrict__ wkv,
                             const float* __restrict__ wo,
                             unsigned short* __restrict__ dq, unsigned short* __restrict__ dkv,
                             unsigned short* __restrict__ dwo) {
    __shared__ float tile[32][33];
    const int b = blockIdx.x;
    const float* src; unsigned short* dst; int R, C, bx, by;
    if (b < 64)       { src = wq;  dst = dq;  R = 256; C = 256; bx = b & 7;  by = b >> 3; }
    else if (b < 256) { const int t = b - 64;  src = wkv; dst = dkv; R = 384; C = 512; bx = t & 15; by = t >> 4; }
    else              { const int t = b - 256; src = wo;  dst = dwo; R = 256; C = 256; bx = t & 7;  by = t >> 3; }
    const int c0 = bx * 32, r0 = by * 32;
    const int tx = threadIdx.x, ty = threadIdx.y;   // 32 x 8
#pragma unroll
    for (int i = 0; i < 32; i += 8)
        tile[ty + i][tx] = src[(size_t)(r0 + ty + i) * C + (c0 + tx)];
    __syncthreads();
#pragma unroll
    for (int i = 0; i < 32; i += 8)
        dst[(size_t)(c0 + ty + i) * R + (r0 + tx)] = f2b(tile[tx][ty + i]);
}

// load 8 consecutive f32, convert, store 8 bf16 (16B) to LDS
__device__ __forceinline__ void ld8f(const float* __restrict__ s, unsigned short* dst) {
    const float4 a = *(const float4*)s;
    const float4 b = *(const float4*)(s + 4);
    unsigned short t[8];
    t[0] = f2b(a.x); t[1] = f2b(a.y); t[2] = f2b(a.z); t[3] = f2b(a.w);
    t[4] = f2b(b.x); t[5] = f2b(b.y); t[6] = f2b(b.z); t[7] = f2b(b.w);
    *(uint4*)dst = *(const uint4*)t;
}

// Fully fused temporal attention: one WG = 2 batch elements, 4 waves.
// Wave w owns heads {2w, 2w+1} (cols [64w, 64w+64) of the K-half / V-half).
// v4: occupancy + loaded-latency fixes.
//  - K/V projection split into two passes (acc 64 AGPR each instead of 128)
//  - Rb/Ob shrunk 16->2 rows (M-padding unnecessary: C row i depends only on
//    A row i; A-frag reads row l15&1, C rows 2..15 are garbage never read)
//  - Qs/lnb LDS freed (shfl broadcast; lnb overlaid on dead Xs)
//  => 52.5 KB LDS, <=170 regs -> 3 blocks/CU, 12 waves/CU (was 8)
//  - naked s_barrier per kc phase-locks the 4 waves so their reads of the
//    same 16KB weight k-slice share L1 (no waitcnt drain; all LDS data was
//    published at barrier #1)
__global__ __launch_bounds__(256, 3) void ta_fused(
    const float* __restrict__ node,
    const float* __restrict__ timef,
    const float* __restrict__ edge,
    const float* __restrict__ nbrnode,
    const float* __restrict__ nbrtime,
    const int* __restrict__ nmask,
    const float* __restrict__ bO,
    const float* __restrict__ gam,
    const float* __restrict__ bet,
    float* __restrict__ out)
{
    __shared__ __align__(16) unsigned short Xs[64 * XSTRIDE];   // 50176 B, X bf16 [row][k]
    __shared__ __align__(16) unsigned short Rb[2 * MSTRIDE];    // residual R rows 0,1
    __shared__ __align__(16) unsigned short Ob[2 * MSTRIDE];    // attention out O rows 0,1
    __shared__ int mk[2][32];
    float* lnb = (float*)Xs;    // [2][256] overlay — Xs dead after V-pass

    const int gb0  = blockIdx.x * 2;
    const int tid  = threadIdx.x;
    const int w    = tid >> 6;
    const int lane = tid & 63;
    const int l15  = lane & 15;
    const int quad = lane >> 4;
    const int arow = (l15 & 1) * MSTRIDE;   // A-frag row for M=2 GEMMs

    // mask stride sniff, parallel OR (no serial dependent-load chain)
    int orv = 0;
#pragma unroll
    for (int i = 1; i < 64; i += 2) orv |= nmask[i];
    const bool m64 = (orv == 0);

    if (tid < 64) {               // R rows: concat(node, time) for b=0,1
        const int b = tid >> 5, s = tid & 31;
        if (s < 16) ld8f(node  + (size_t)(gb0 + b) * 128 + s * 8,        &Rb[b * MSTRIDE + s * 8]);
        else        ld8f(timef + (size_t)(gb0 + b) * 128 + (s - 16) * 8, &Rb[b * MSTRIDE + s * 8]);
    } else if (tid < 128) {       // neighbor masks
        const int t = tid - 64, b = t >> 5, n = t & 31;
        const size_t j = (size_t)(gb0 + b) * 32 + n;
        mk[b][n] = m64 ? nmask[2 * j] : nmask[j];
    }
    // ---- stage X = concat(nbr_node, edge, nbr_time) bf16 [64][384], once ----
#pragma unroll
    for (int i = 0; i < 12; i++) {
        const int g  = i * 256 + tid;        // 0..3071
        const int r  = g / 48, c8 = g % 48;  // row 0..63, 8-elem chunk 0..47
        const float* base; int koff;
        if (c8 < 16)      { base = nbrnode; koff = c8 * 8; }
        else if (c8 < 32) { base = edge;    koff = (c8 - 16) * 8; }
        else              { base = nbrtime; koff = (c8 - 32) * 8; }
        ld8f(base + (size_t)(gb0 * 32 + r) * 128 + koff, &Xs[r * XSTRIDE + c8 * 8]);
    }
    __syncthreads();   // barrier #1: Rb/Xs/mk visible to all waves

    const unsigned short* wq  = g_WQT  + (size_t)(w * 64 + l15) * 256 + quad * 8;
    const unsigned short* wkv = g_WKVT + (size_t)(w * 64 + l15) * 384 + quad * 8;
    const unsigned short* wo  = g_WOT  + (size_t)(w * 64 + l15) * 256 + quad * 8;
    const f32x4 zero4 = {0.0f, 0.0f, 0.0f, 0.0f};

    // ================= Phase Q: Q = R @ W_Q  (M=2, rows 0,1 in regs at quad 0) ==========
    f32x4 accq[4];
#pragma unroll
    for (int ct = 0; ct < 4; ct++) accq[ct] = zero4;
    {
        bf16x8 bq[2][4];
#pragma unroll
        for (int p = 0; p < 2; p++)
#pragma unroll
            for (int ct = 0; ct < 4; ct++)
                bq[p][ct] = *(const bf16x8*)(wq + (size_t)(ct * 16) * 256 + p * 32);
#pragma unroll
        for (int kc = 0; kc < 8; kc++) {
            const int s = kc & 1;
            __builtin_amdgcn_s_barrier();   // phase-lock (no data dependence)
            const bf16x8 aq = *(const bf16x8*)(&Rb[arow + kc * 32 + quad * 8]);
#pragma unroll
            for (int ct = 0; ct < 4; ct++)
                accq[ct] = __builtin_amdgcn_mfma_f32_16x16x32_bf16(aq, bq[s][ct], accq[ct], 0, 0, 0);
            if (kc + 2 < 8) {
#pragma unroll
                for (int ct = 0; ct < 4; ct++)
                    bq[s][ct] = *(const bf16x8*)(wq + (size_t)(ct * 16) * 256 + (kc + 2) * 32);
            }
        }
    }

    // ================= K-pass: K = X @ W_KV[:, :256]  (64 x 256, K=384) =================
    f32x4 accK[4][4];
#pragma unroll
    for (int rt = 0; rt < 4; rt++)
#pragma unroll
        for (int ct = 0; ct < 4; ct++) accK[rt][ct] = zero4;
    {
        bf16x8 bK[2][4];
#pragma unroll
        for (int p = 0; p < 2; p++)
#pragma unroll
            for (int ct = 0; ct < 4; ct++)
                bK[p][ct] = *(const bf16x8*)(wkv + (size_t)(ct * 16) * 384 + p * 32);
#pragma unroll
        for (int kc = 0; kc < 12; kc++) {
            const int s = kc & 1;
            __builtin_amdgcn_s_barrier();   // phase-lock: 4 waves share the 16KB k-slice in L1
            bf16x8 af[4];
#pragma unroll
            for (int rt = 0; rt < 4; rt++)
                af[rt] = *(const bf16x8*)(&Xs[(rt * 16 + l15) * XSTRIDE + kc * 32 + quad * 8]);
            __builtin_amdgcn_s_setprio(1);
#pragma unroll
            for (int ct = 0; ct < 4; ct++)
#pragma unroll
                for (int rt = 0; rt < 4; rt++)
                    accK[rt][ct] = __builtin_amdgcn_mfma_f32_16x16x32_bf16(af[rt], bK[s][ct], accK[rt][ct], 0, 0, 0);
            __builtin_amdgcn_s_setprio(0);
            if (kc + 2 < 12) {
#pragma unroll
                for (int ct = 0; ct < 4; ct++)
                    bK[s][ct] = *(const bf16x8*)(wkv + (size_t)(ct * 16) * 384 + (kc + 2) * 32);
            }
        }
    }

    // ================= softmax: scores + masked softmax (C-layout) ======================
    // accK: lane holds K[row n = rt*16+quad*4+rg][dcol = 64w+ct*16+l15].
    float aw[2][2][2][4];
    const float scl = 0.17677669529663687f;   // 32^-0.5
#pragma unroll
    for (int bb = 0; bb < 2; bb++) {
        float qv[4];
#pragma unroll
        for (int ct = 0; ct < 4; ct++) qv[ct] = __shfl(accq[ct][bb], l15, 64);
#pragma unroll
        for (int hl = 0; hl < 2; hl++) {
            float sv[2][4];
#pragma unroll
            for (int rtl = 0; rtl < 2; rtl++) {
                const int rt = bb * 2 + rtl;
#pragma unroll
                for (int rg = 0; rg < 4; rg++)
                    sv[rtl][rg] = accK[rt][2 * hl][rg] * qv[2 * hl]
                                + accK[rt][2 * hl + 1][rg] * qv[2 * hl + 1];
            }
#pragma unroll
            for (int m = 1; m <= 8; m <<= 1)
#pragma unroll
                for (int rtl = 0; rtl < 2; rtl++)
#pragma unroll
                    for (int rg = 0; rg < 4; rg++)
                        sv[rtl][rg] += __shfl_xor(sv[rtl][rg], m, 64);
            float mx = -3.0e38f;
#pragma unroll
            for (int rtl = 0; rtl < 2; rtl++)
#pragma unroll
                for (int rg = 0; rg < 4; rg++) {
                    const int n = rtl * 16 + quad * 4 + rg;
                    sv[rtl][rg] = (mk[bb][n] != 0) ? sv[rtl][rg] * scl : -1.0e10f;
                    mx = fmaxf(mx, sv[rtl][rg]);
                }
            mx = fmaxf(mx, __shfl_xor(mx, 16, 64));
            mx = fmaxf(mx, __shfl_xor(mx, 32, 64));
            float sum = 0.0f;
#pragma unroll
            for (int rtl = 0; rtl < 2; rtl++)
#pragma unroll
                for (int rg = 0; rg < 4; rg++) {
                    const float e = __expf(sv[rtl][rg] - mx);
                    aw[bb][hl][rtl][rg] = e;
                    sum += e;
                }
            sum += __shfl_xor(sum, 16, 64);
            sum += __shfl_xor(sum, 32, 64);
            const float inv = 1.0f / sum;
#pragma unroll
            for (int rtl = 0; rtl < 2; rtl++)
#pragma unroll
                for (int rg = 0; rg < 4; rg++)
                    aw[bb][hl][rtl][rg] *= inv;
        }
    }

    // ================= V-pass: V = X @ W_KV[:, 256:]  (64 x 256, K=384) =================
    f32x4 accV[4][4];
#pragma unroll
    for (int rt = 0; rt < 4; rt++)
#pragma unroll
        for (int ct = 0; ct < 4; ct++) accV[rt][ct] = zero4;
    {
        bf16x8 bV[2][4];
#pragma unroll
        for (int p = 0; p < 2; p++)
#pragma unroll
            for (int ct = 0; ct < 4; ct++)
                bV[p][ct] = *(const bf16x8*)(wkv + (size_t)(256 + ct * 16) * 384 + p * 32);
#pragma unroll
        for (int kc = 0; kc < 12; kc++) {
            const int s = kc & 1;
            __builtin_amdgcn_s_barrier();   // phase-lock
            bf16x8 af[4];
#pragma unroll
            for (int rt = 0; rt < 4; rt++)
                af[rt] = *(const bf16x8*)(&Xs[(rt * 16 + l15) * XSTRIDE + kc * 32 + quad * 8]);
            __builtin_amdgcn_s_setprio(1);
#pragma unroll
            for (int ct = 0; ct < 4; ct++)
#pragma unroll
                for (int rt = 0; rt < 4; rt++)
                    accV[rt][ct] = __builtin_amdgcn_mfma_f32_16x16x32_bf16(af[rt], bV[s][ct], accV[rt][ct], 0, 0, 0);
            __builtin_amdgcn_s_setprio(0);
            if (kc + 2 < 12) {
#pragma unroll
                for (int ct = 0; ct < 4; ct++)
                    bV[s][ct] = *(const bf16x8*)(wkv + (size_t)(256 + ct * 16) * 384 + (kc + 2) * 32);
            }
        }
    }

    // ================= PV: O = A @ V  (reduce over rows n -> quad shuffles) =============
#pragma unroll
    for (int bb = 0; bb < 2; bb++)
#pragma unroll
        for (int hl = 0; hl < 2; hl++)
#pragma unroll
            for (int ctl = 0; ctl < 2; ctl++) {
                const int ct = hl * 2 + ctl;
                float o = 0.0f;
#pragma unroll
                for (int rtl = 0; rtl < 2; rtl++)
#pragma unroll
                    for (int rg = 0; rg < 4; rg++)
                        o += aw[bb][hl][rtl][rg] * accV[bb * 2 + rtl][ct][rg];
                o += __shfl_xor(o, 16, 64);
                o += __shfl_xor(o, 32, 64);
                if (quad == 0) {
                    const int col = (w * 2 + hl) * 32 + ctl * 16 + l15;
                    Ob[bb * MSTRIDE + col] = f2b(o);
                }
            }
    __syncthreads();   // barrier #2: all waves' O columns visible (V-pass also done -> Xs dead)

    // ================= O-proj: out = O @ W_O + b_O + R, then LayerNorm ==================
    f32x4 acco[4];
#pragma unroll
    for (int ct = 0; ct < 4; ct++) acco[ct] = zero4;
    {
        bf16x8 bo[2][4];
#pragma unroll
        for (int p = 0; p < 2; p++)
#pragma unroll
            for (int ct = 0; ct < 4; ct++)
                bo[p][ct] = *(const bf16x8*)(wo + (size_t)(ct * 16) * 256 + p * 32);
#pragma unroll
        for (int kc = 0; kc < 8; kc++) {
            const int s = kc & 1;
            __builtin_amdgcn_s_barrier();   // phase-lock
            const bf16x8 ao = *(const bf16x8*)(&Ob[arow + kc * 32 + quad * 8]);
#pragma unroll
            for (int ct = 0; ct < 4; ct++)
                acco[ct] = __builtin_amdgcn_mfma_f32_16x16x32_bf16(ao, bo[s][ct], acco[ct], 0, 0, 0);
            if (kc + 2 < 8) {
#pragma unroll
                for (int ct = 0; ct < 4; ct++)
                    bo[s][ct] = *(const bf16x8*)(wo + (size_t)(ct * 16) * 256 + (kc + 2) * 32);
            }
        }
    }
    if (quad == 0) {
#pragma unroll
        for (int ct = 0; ct < 4; ct++) {
#pragma unroll
            for (int r = 0; r < 2; r++) {
                const int col = w * 64 + ct * 16 + l15;
                lnb[r * 256 + col] = acco[ct][r] + bO[col] + b2f(Rb[r * MSTRIDE + col]);
            }
        }
    }
    __syncthreads();   // barrier #3: lnb complete

    if (w < 2) {   // wave 0 -> batch 0, wave 1 -> batch 1
        const int bb = w;
        float x[4]; float s = 0.0f;
#pragma unroll
        for (int i = 0; i < 4; i++) { x[i] = lnb[bb * 256 + lane + i * 64]; s += x[i]; }
#pragma unroll
        for (int m = 1; m <= 32; m <<= 1) s += __shfl_xor(s, m, 64);
        const float mu = s * (1.0f / 256.0f);
        float s2 = 0.0f;
#pragma unroll
        for (int i = 0; i < 4; i++) { const float d = x[i] - mu; s2 += d * d; }
#pragma unroll
        for (int m = 1; m <= 32; m <<= 1) s2 += __shfl_xor(s2, m, 64);
        const float rstd = rsqrtf(s2 * (1.0f / 256.0f) + 1e-5f);
#pragma unroll
        for (int i = 0; i < 4; i++) {
            const int col = lane + i * 64;
            out[(size_t)(gb0 + bb) * 256 + col] =
                (x[i] - mu) * rstd * gam[col] + bet[col];
        }
    }
}

extern "C" void kernel_launch(void* const* d_in, const int* in_sizes, int n_in,
                              void* d_out, int out_size, void* d_ws, size_t ws_size,
                              hipStream_t stream) {
    const float* node    = (const float*)d_in[0];
    const float* timef   = (const float*)d_in[1];
    const float* edge    = (const float*)d_in[2];
    const float* nbrnode = (const float*)d_in[3];
    const float* nbrtime = (const float*)d_in[4];
    const int*   nmask   = (const int*)d_in[5];
    const float* W_Q     = (const float*)d_in[6];
    const float* W_KV    = (const float*)d_in[7];
    const float* W_O     = (const float*)d_in[8];
    const float* bO      = (const float*)d_in[9];
    const float* gam     = (const float*)d_in[10];
    const float* bet     = (const float*)d_in[11];

    unsigned short *wqt, *wkvt, *wot;
    hipGetSymbolAddress((void**)&wqt,  HIP_SYMBOL(g_WQT));
    hipGetSymbolAddress((void**)&wkvt, HIP_SYMBOL(g_WKVT));
    hipGetSymbolAddress((void**)&wot,  HIP_SYMBOL(g_WOT));

    transcvt_all<<<320, dim3(32, 8), 0, stream>>>(W_Q, W_KV, W_O, wqt, wkvt, wot);

    ta_fused<<<4096, 256, 0, stream>>>(node, timef, edge, nbrnode, nbrtime, nmask,
                                       bO, gam, bet, (float*)d_out);
}

// Round 4
// 616.478 us; speedup vs baseline: 1.1066x; 1.0790x over previous
//
#include <hip/hip_runtime.h>

typedef __attribute__((ext_vector_type(8))) short bf16x8;
typedef __attribute__((ext_vector_type(4))) float f32x4;

#define MSTRIDE 264   // Rb/Ob row stride in shorts (528B, 16B aligned, bank-balanced)
#define XSTRIDE 392   // Xs row stride in shorts (784B, 16B aligned, bank-balanced)

// Pre-converted transposed weights (bf16, [n][k]) — module-scope device memory,
// rewritten every call by transcvt_all. L2-resident (640 KB total).
__device__ __align__(16) unsigned short g_WQT[256 * 256];
__device__ __align__(16) unsigned short g_WKVT[512 * 384];
__device__ __align__(16) unsigned short g_WOT[256 * 256];

__device__ __forceinline__ float b2f(unsigned short u) {
    union { unsigned int i; float f; } v; v.i = ((unsigned int)u) << 16; return v.f;
}
__device__ __forceinline__ unsigned short f2b(float f) {
    union { float f; unsigned int i; } v; v.f = f;
    unsigned int x = v.i;
    return (unsigned short)((x + 0x7fffu + ((x >> 16) & 1u)) >> 16);  // RNE
}

// One launch transposes+converts all three weight matrices.
// dst[c][r] = bf16(src[r][c]); tiles flattened into blockIdx.x.
__global__ void transcvt_all(const float* __restrict__ wq, const float* __restrict__ wkv,
                             const float* __restrict__ wo,
                             unsigned short* __restrict__ dq, unsigned short* __restrict__ dkv,
                             unsigned short* __restrict__ dwo) {
    __shared__ float tile[32][33];
    const int b = blockIdx.x;
    const float* src; unsigned short* dst; int R, C, bx, by;
    if (b < 64)       { src = wq;  dst = dq;  R = 256; C = 256; bx = b & 7;  by = b >> 3; }
    else if (b < 256) { const int t = b - 64;  src = wkv; dst = dkv; R = 384; C = 512; bx = t & 15; by = t >> 4; }
    else              { const int t = b - 256; src = wo;  dst = dwo; R = 256; C = 256; bx = t & 7;  by = t >> 3; }
    const int c0 = bx * 32, r0 = by * 32;
    const int tx = threadIdx.x, ty = threadIdx.y;   // 32 x 8
#pragma unroll
    for (int i = 0; i < 32; i += 8)
        tile[ty + i][tx] = src[(size_t)(r0 + ty + i) * C + (c0 + tx)];
    __syncthreads();
#pragma unroll
    for (int i = 0; i < 32; i += 8)
        dst[(size_t)(c0 + ty + i) * R + (r0 + tx)] = f2b(tile[tx][ty + i]);
}

// load 8 consecutive f32, convert, store 8 bf16 (16B) to LDS
__device__ __forceinline__ void ld8f(const float* __restrict__ s, unsigned short* dst) {
    const float4 a = *(const float4*)s;
    const float4 b = *(const float4*)(s + 4);
    unsigned short t[8];
    t[0] = f2b(a.x); t[1] = f2b(a.y); t[2] = f2b(a.z); t[3] = f2b(a.w);
    t[4] = f2b(b.x); t[5] = f2b(b.y); t[6] = f2b(b.z); t[7] = f2b(b.w);
    *(uint4*)dst = *(const uint4*)t;
}

// Fully fused temporal attention.
// v5: M=4 batch rows per block (was 2) — the kernel is bytes/CU-bound at the
// ~10-11 B/cyc/CU vector-path ceiling (r1/r2/r3 all pinned at 442 us = 11.9 MB/CU),
// and the 640 KB/block weight read is 86% of traffic. Doubling M halves
// weight-bytes per batch row: 8 blocks/CU x (640KB W + 196KB X) = 6.8 MB/CU.
// Cost: X-bf16 LDS = 98 KB -> 1 block/CU, 4 waves. r3 proved wave count is not
// the limiter. __launch_bounds__(256,1): full register file (accK/accV = 128
// AGPR each, non-overlapping phases), no spill.
// Wave w owns heads {2w, 2w+1} (cols [64w, 64w+64) of the K-half / V-half).
__global__ __launch_bounds__(256, 1) void ta_fused(
    const float* __restrict__ node,
    const float* __restrict__ timef,
    const float* __restrict__ edge,
    const float* __restrict__ nbrnode,
    const float* __restrict__ nbrtime,
    const int* __restrict__ nmask,
    const float* __restrict__ bO,
    const float* __restrict__ gam,
    const float* __restrict__ bet,
    float* __restrict__ out)
{
    __shared__ __align__(16) unsigned short Xs[128 * XSTRIDE];  // 100352 B, X bf16 [row][k]
    __shared__ __align__(16) unsigned short Rb[4 * MSTRIDE];    // residual R rows 0..3
    __shared__ __align__(16) unsigned short Ob[4 * MSTRIDE];    // attention out O rows 0..3
    __shared__ int mk[4][32];
    float* lnb = (float*)Xs;    // [4][256] overlay — Xs dead after V-pass

    const int gb0  = blockIdx.x * 4;
    const int tid  = threadIdx.x;
    const int w    = tid >> 6;
    const int lane = tid & 63;
    const int l15  = lane & 15;
    const int quad = lane >> 4;
    const int arow = (l15 & 3) * MSTRIDE;   // A-frag row for M=4 GEMMs (C rows 4..15 garbage)

    // mask stride sniff, parallel OR (no serial dependent-load chain)
    int orv = 0;
#pragma unroll
    for (int i = 1; i < 64; i += 2) orv |= nmask[i];
    const bool m64 = (orv == 0);

    if (tid < 128) {              // R rows: concat(node, time) for b=0..3
        const int b = tid >> 5, s = tid & 31;
        if (s < 16) ld8f(node  + (size_t)(gb0 + b) * 128 + s * 8,        &Rb[b * MSTRIDE + s * 8]);
        else        ld8f(timef + (size_t)(gb0 + b) * 128 + (s - 16) * 8, &Rb[b * MSTRIDE + s * 8]);
    } else {                      // neighbor masks for b=0..3
        const int t = tid - 128, b = t >> 5, n = t & 31;
        const size_t j = (size_t)(gb0 + b) * 32 + n;
        mk[b][n] = m64 ? nmask[2 * j] : nmask[j];
    }
    // ---- stage X = concat(nbr_node, edge, nbr_time) bf16 [128][384], once ----
#pragma unroll
    for (int i = 0; i < 24; i++) {
        const int g  = i * 256 + tid;        // 0..6143
        const int r  = g / 48, c8 = g % 48;  // row 0..127, 8-elem chunk 0..47
        const float* base; int koff;
        if (c8 < 16)      { base = nbrnode; koff = c8 * 8; }
        else if (c8 < 32) { base = edge;    koff = (c8 - 16) * 8; }
        else              { base = nbrtime; koff = (c8 - 32) * 8; }
        ld8f(base + (size_t)(gb0 * 32 + r) * 128 + koff, &Xs[r * XSTRIDE + c8 * 8]);
    }
    __syncthreads();   // barrier #1: Rb/Xs/mk visible to all waves

    const unsigned short* wq  = g_WQT  + (size_t)(w * 64 + l15) * 256 + quad * 8;
    const unsigned short* wkv = g_WKVT + (size_t)(w * 64 + l15) * 384 + quad * 8;
    const unsigned short* wo  = g_WOT  + (size_t)(w * 64 + l15) * 256 + quad * 8;
    const f32x4 zero4 = {0.0f, 0.0f, 0.0f, 0.0f};

    // ================= Phase Q: Q = R @ W_Q  (M=4, rows 0..3 in regs at quad 0) =========
    f32x4 accq[4];
#pragma unroll
    for (int ct = 0; ct < 4; ct++) accq[ct] = zero4;
    {
        bf16x8 bq[2][4];
#pragma unroll
        for (int p = 0; p < 2; p++)
#pragma unroll
            for (int ct = 0; ct < 4; ct++)
                bq[p][ct] = *(const bf16x8*)(wq + (size_t)(ct * 16) * 256 + p * 32);
#pragma unroll
        for (int kc = 0; kc < 8; kc++) {
            const int s = kc & 1;
            const bf16x8 aq = *(const bf16x8*)(&Rb[arow + kc * 32 + quad * 8]);
#pragma unroll
            for (int ct = 0; ct < 4; ct++)
                accq[ct] = __builtin_amdgcn_mfma_f32_16x16x32_bf16(aq, bq[s][ct], accq[ct], 0, 0, 0);
            if (kc + 2 < 8) {
#pragma unroll
                for (int ct = 0; ct < 4; ct++)
                    bq[s][ct] = *(const bf16x8*)(wq + (size_t)(ct * 16) * 256 + (kc + 2) * 32);
            }
        }
    }

    // ================= K-pass: K = X @ W_KV[:, :256]  (128 x 256, K=384) ================
    f32x4 accK[8][4];
#pragma unroll
    for (int rt = 0; rt < 8; rt++)
#pragma unroll
        for (int ct = 0; ct < 4; ct++) accK[rt][ct] = zero4;
    {
        bf16x8 bK[2][4];
#pragma unroll
        for (int p = 0; p < 2; p++)
#pragma unroll
            for (int ct = 0; ct < 4; ct++)
                bK[p][ct] = *(const bf16x8*)(wkv + (size_t)(ct * 16) * 384 + p * 32);
#pragma unroll
        for (int kc = 0; kc < 12; kc++) {
            const int s = kc & 1;
            bf16x8 af[8];
#pragma unroll
            for (int rt = 0; rt < 8; rt++)
                af[rt] = *(const bf16x8*)(&Xs[(rt * 16 + l15) * XSTRIDE + kc * 32 + quad * 8]);
            __builtin_amdgcn_s_setprio(1);
#pragma unroll
            for (int ct = 0; ct < 4; ct++)
#pragma unroll
                for (int rt = 0; rt < 8; rt++)
                    accK[rt][ct] = __builtin_amdgcn_mfma_f32_16x16x32_bf16(af[rt], bK[s][ct], accK[rt][ct], 0, 0, 0);
            __builtin_amdgcn_s_setprio(0);
            if (kc + 2 < 12) {
#pragma unroll
                for (int ct = 0; ct < 4; ct++)
                    bK[s][ct] = *(const bf16x8*)(wkv + (size_t)(ct * 16) * 384 + (kc + 2) * 32);
            }
        }
    }

    // ================= softmax: scores + masked softmax (C-layout) ======================
    // accK: lane holds K[row n = rt*16+quad*4+rg][dcol = 64w+ct*16+l15]; batch bb = rt>>1.
    float aw[4][2][2][4];
    const float scl = 0.17677669529663687f;   // 32^-0.5
#pragma unroll
    for (int bb = 0; bb < 4; bb++) {
        float qv[4];
#pragma unroll
        for (int ct = 0; ct < 4; ct++) qv[ct] = __shfl(accq[ct][bb], l15, 64);
#pragma unroll
        for (int hl = 0; hl < 2; hl++) {
            float sv[2][4];
#pragma unroll
            for (int rtl = 0; rtl < 2; rtl++) {
                const int rt = bb * 2 + rtl;
#pragma unroll
                for (int rg = 0; rg < 4; rg++)
                    sv[rtl][rg] = accK[rt][2 * hl][rg] * qv[2 * hl]
                                + accK[rt][2 * hl + 1][rg] * qv[2 * hl + 1];
            }
#pragma unroll
            for (int m = 1; m <= 8; m <<= 1)
#pragma unroll
                for (int rtl = 0; rtl < 2; rtl++)
#pragma unroll
                    for (int rg = 0; rg < 4; rg++)
                        sv[rtl][rg] += __shfl_xor(sv[rtl][rg], m, 64);
            float mx = -3.0e38f;
#pragma unroll
            for (int rtl = 0; rtl < 2; rtl++)
#pragma unroll
                for (int rg = 0; rg < 4; rg++) {
                    const int n = rtl * 16 + quad * 4 + rg;
                    sv[rtl][rg] = (mk[bb][n] != 0) ? sv[rtl][rg] * scl : -1.0e10f;
                    mx = fmaxf(mx, sv[rtl][rg]);
                }
            mx = fmaxf(mx, __shfl_xor(mx, 16, 64));
            mx = fmaxf(mx, __shfl_xor(mx, 32, 64));
            float sum = 0.0f;
#pragma unroll
            for (int rtl = 0; rtl < 2; rtl++)
#pragma unroll
                for (int rg = 0; rg < 4; rg++) {
                    const float e = __expf(sv[rtl][rg] - mx);
                    aw[bb][hl][rtl][rg] = e;
                    sum += e;
                }
            sum += __shfl_xor(sum, 16, 64);
            sum += __shfl_xor(sum, 32, 64);
            const float inv = 1.0f / sum;
#pragma unroll
            for (int rtl = 0; rtl < 2; rtl++)
#pragma unroll
                for (int rg = 0; rg < 4; rg++)
                    aw[bb][hl][rtl][rg] *= inv;
        }
    }

    // ================= V-pass: V = X @ W_KV[:, 256:]  (128 x 256, K=384) ================
    f32x4 accV[8][4];
#pragma unroll
    for (int rt = 0; rt < 8; rt++)
#pragma unroll
        for (int ct = 0; ct < 4; ct++) accV[rt][ct] = zero4;
    {
        bf16x8 bV[2][4];
#pragma unroll
        for (int p = 0; p < 2; p++)
#pragma unroll
            for (int ct = 0; ct < 4; ct++)
                bV[p][ct] = *(const bf16x8*)(wkv + (size_t)(256 + ct * 16) * 384 + p * 32);
#pragma unroll
        for (int kc = 0; kc < 12; kc++) {
            const int s = kc & 1;
            bf16x8 af[8];
#pragma unroll
            for (int rt = 0; rt < 8; rt++)
                af[rt] = *(const bf16x8*)(&Xs[(rt * 16 + l15) * XSTRIDE + kc * 32 + quad * 8]);
            __builtin_amdgcn_s_setprio(1);
#pragma unroll
            for (int ct = 0; ct < 4; ct++)
#pragma unroll
                for (int rt = 0; rt < 8; rt++)
                    accV[rt][ct] = __builtin_amdgcn_mfma_f32_16x16x32_bf16(af[rt], bV[s][ct], accV[rt][ct], 0, 0, 0);
            __builtin_amdgcn_s_setprio(0);
            if (kc + 2 < 12) {
#pragma unroll
                for (int ct = 0; ct < 4; ct++)
                    bV[s][ct] = *(const bf16x8*)(wkv + (size_t)(256 + ct * 16) * 384 + (kc + 2) * 32);
            }
        }
    }

    // ================= PV: O = A @ V  (reduce over rows n -> quad shuffles) =============
#pragma unroll
    for (int bb = 0; bb < 4; bb++)
#pragma unroll
        for (int hl = 0; hl < 2; hl++)
#pragma unroll
            for (int ctl = 0; ctl < 2; ctl++) {
                const int ct = hl * 2 + ctl;
                float o = 0.0f;
#pragma unroll
                for (int rtl = 0; rtl < 2; rtl++)
#pragma unroll
                    for (int rg = 0; rg < 4; rg++)
                        o += aw[bb][hl][rtl][rg] * accV[bb * 2 + rtl][ct][rg];
                o += __shfl_xor(o, 16, 64);
                o += __shfl_xor(o, 32, 64);
                if (quad == 0) {
                    const int col = (w * 2 + hl) * 32 + ctl * 16 + l15;
                    Ob[bb * MSTRIDE + col] = f2b(o);
                }
            }
    __syncthreads();   // barrier #2: all waves' O columns visible (V-pass done -> Xs dead)

    // ================= O-proj: out = O @ W_O + b_O + R, then LayerNorm ==================
    f32x4 acco[4];
#pragma unroll
    for (int ct = 0; ct < 4; ct++) acco[ct] = zero4;
    {
        bf16x8 bo[2][4];
#pragma unroll
        for (int p = 0; p < 2; p++)
#pragma unroll
            for (int ct = 0; ct < 4; ct++)
                bo[p][ct] = *(const bf16x8*)(wo + (size_t)(ct * 16) * 256 + p * 32);
#pragma unroll
        for (int kc = 0; kc < 8; kc++) {
            const int s = kc & 1;
            const bf16x8 ao = *(const bf16x8*)(&Ob[arow + kc * 32 + quad * 8]);
#pragma unroll
            for (int ct = 0; ct < 4; ct++)
                acco[ct] = __builtin_amdgcn_mfma_f32_16x16x32_bf16(ao, bo[s][ct], acco[ct], 0, 0, 0);
            if (kc + 2 < 8) {
#pragma unroll
                for (int ct = 0; ct < 4; ct++)
                    bo[s][ct] = *(const bf16x8*)(wo + (size_t)(ct * 16) * 256 + (kc + 2) * 32);
            }
        }
    }
    if (quad == 0) {
#pragma unroll
        for (int ct = 0; ct < 4; ct++) {
#pragma unroll
            for (int r = 0; r < 4; r++) {
                const int col = w * 64 + ct * 16 + l15;
                lnb[r * 256 + col] = acco[ct][r] + bO[col] + b2f(Rb[r * MSTRIDE + col]);
            }
        }
    }
    __syncthreads();   // barrier #3: lnb complete

    {   // wave w -> batch row w (4 rows, 4 waves)
        const int bb = w;
        float x[4]; float s = 0.0f;
#pragma unroll
        for (int i = 0; i < 4; i++) { x[i] = lnb[bb * 256 + lane + i * 64]; s += x[i]; }
#pragma unroll
        for (int m = 1; m <= 32; m <<= 1) s += __shfl_xor(s, m, 64);
        const float mu = s * (1.0f / 256.0f);
        float s2 = 0.0f;
#pragma unroll
        for (int i = 0; i < 4; i++) { const float d = x[i] - mu; s2 += d * d; }
#pragma unroll
        for (int m = 1; m <= 32; m <<= 1) s2 += __shfl_xor(s2, m, 64);
        const float rstd = rsqrtf(s2 * (1.0f / 256.0f) + 1e-5f);
#pragma unroll
        for (int i = 0; i < 4; i++) {
            const int col = lane + i * 64;
            out[(size_t)(gb0 + bb) * 256 + col] =
                (x[i] - mu) * rstd * gam[col] + bet[col];
        }
    }
}

extern "C" void kernel_launch(void* const* d_in, const int* in_sizes, int n_in,
                              void* d_out, int out_size, void* d_ws, size_t ws_size,
                              hipStream_t stream) {
    const float* node    = (const float*)d_in[0];
    const float* timef   = (const float*)d_in[1];
    const float* edge    = (const float*)d_in[2];
    const float* nbrnode = (const float*)d_in[3];
    const float* nbrtime = (const float*)d_in[4];
    const int*   nmask   = (const int*)d_in[5];
    const float* W_Q     = (const float*)d_in[6];
    const float* W_KV    = (const float*)d_in[7];
    const float* W_O     = (const float*)d_in[8];
    const float* bO      = (const float*)d_in[9];
    const float* gam     = (const float*)d_in[10];
    const float* bet     = (const float*)d_in[11];

    unsigned short *wqt, *wkvt, *wot;
    hipGetSymbolAddress((void**)&wqt,  HIP_SYMBOL(g_WQT));
    hipGetSymbolAddress((void**)&wkvt, HIP_SYMBOL(g_WKVT));
    hipGetSymbolAddress((void**)&wot,  HIP_SYMBOL(g_WOT));

    transcvt_all<<<320, dim3(32, 8), 0, stream>>>(W_Q, W_KV, W_O, wqt, wkvt, wot);

    ta_fused<<<2048, 256, 0, stream>>>(node, timef, edge, nbrnode, nbrtime, nmask,
                                       bO, gam, bet, (float*)d_out);
}

// Round 5
// 547.556 us; speedup vs baseline: 1.2459x; 1.1259x over previous
//
#include <hip/hip_runtime.h>

typedef __attribute__((ext_vector_type(8))) short bf16x8;
typedef __attribute__((ext_vector_type(4))) float f32x4;

#define MSTRIDE 264   // Rb/Ob row stride in shorts (528B, 16B aligned, bank-balanced)
#define XSTRIDE 392   // Xs row stride in shorts (784B, 16B aligned, bank-balanced)

// Pre-converted transposed weights (bf16, [n][k]) — module-scope device memory,
// rewritten every call by transcvt_all. L2-resident (640 KB total).
__device__ __align__(16) unsigned short g_WQT[256 * 256];
__device__ __align__(16) unsigned short g_WKVT[512 * 384];
__device__ __align__(16) unsigned short g_WOT[256 * 256];

__device__ __forceinline__ float b2f(unsigned short u) {
    union { unsigned int i; float f; } v; v.i = ((unsigned int)u) << 16; return v.f;
}
__device__ __forceinline__ unsigned short f2b(float f) {
    union { float f; unsigned int i; } v; v.f = f;
    unsigned int x = v.i;
    return (unsigned short)((x + 0x7fffu + ((x >> 16) & 1u)) >> 16);  // RNE
}

// One launch transposes+converts all three weight matrices.
// dst[c][r] = bf16(src[r][c]); tiles flattened into blockIdx.x.
__global__ void transcvt_all(const float* __restrict__ wq, const float* __restrict__ wkv,
                             const float* __restrict__ wo,
                             unsigned short* __restrict__ dq, unsigned short* __restrict__ dkv,
                             unsigned short* __restrict__ dwo) {
    __shared__ float tile[32][33];
    const int b = blockIdx.x;
    const float* src; unsigned short* dst; int R, C, bx, by;
    if (b < 64)       { src = wq;  dst = dq;  R = 256; C = 256; bx = b & 7;  by = b >> 3; }
    else if (b < 256) { const int t = b - 64;  src = wkv; dst = dkv; R = 384; C = 512; bx = t & 15; by = t >> 4; }
    else              { const int t = b - 256; src = wo;  dst = dwo; R = 256; C = 256; bx = t & 7;  by = t >> 3; }
    const int c0 = bx * 32, r0 = by * 32;
    const int tx = threadIdx.x, ty = threadIdx.y;   // 32 x 8
#pragma unroll
    for (int i = 0; i < 32; i += 8)
        tile[ty + i][tx] = src[(size_t)(r0 + ty + i) * C + (c0 + tx)];
    __syncthreads();
#pragma unroll
    for (int i = 0; i < 32; i += 8)
        dst[(size_t)(c0 + ty + i) * R + (r0 + tx)] = f2b(tile[tx][ty + i]);
}

// load 8 consecutive f32, convert, store 8 bf16 (16B) to LDS
__device__ __forceinline__ void ld8f(const float* __restrict__ s, unsigned short* dst) {
    const float4 a = *(const float4*)s;
    const float4 b = *(const float4*)(s + 4);
    unsigned short t[8];
    t[0] = f2b(a.x); t[1] = f2b(a.y); t[2] = f2b(a.z); t[3] = f2b(a.w);
    t[4] = f2b(b.x); t[5] = f2b(b.y); t[6] = f2b(b.z); t[7] = f2b(b.w);
    *(uint4*)dst = *(const uint4*)t;
}

// Fully fused temporal attention.
// v6: M=4, 512 threads / 8 waves (was 256/4). v5 showed the M=4 byte reduction
// is real (442->388) but 1 wave/SIMD exposes all L2 weight-load latency
// (MfmaUtil*dur == algorithm MFMA time at peak -> pure feeding problem).
// 8 waves = 2 waves/SIMD restores TLP at IDENTICAL bytes and LDS: wave w owns
// head w (32 cols) so per-wave acc halves (accK/accV = 32 AGPR each),
// register peak ~180 < 256 -> 2 waves/SIMD legal by regs.
__global__ __launch_bounds__(512, 2) void ta_fused(
    const float* __restrict__ node,
    const float* __restrict__ timef,
    const float* __restrict__ edge,
    const float* __restrict__ nbrnode,
    const float* __restrict__ nbrtime,
    const int* __restrict__ nmask,
    const float* __restrict__ bO,
    const float* __restrict__ gam,
    const float* __restrict__ bet,
    float* __restrict__ out)
{
    __shared__ __align__(16) unsigned short Xs[128 * XSTRIDE];  // 100352 B, X bf16 [row][k]
    __shared__ __align__(16) unsigned short Rb[4 * MSTRIDE];    // residual R rows 0..3
    __shared__ __align__(16) unsigned short Ob[4 * MSTRIDE];    // attention out O rows 0..3
    __shared__ int mk[4][32];
    float* lnb = (float*)Xs;    // [4][256] overlay — Xs dead after V-pass

    const int gb0  = blockIdx.x * 4;
    const int tid  = threadIdx.x;
    const int w    = tid >> 6;          // wave 0..7 = head 0..7
    const int lane = tid & 63;
    const int l15  = lane & 15;
    const int quad = lane >> 4;
    const int arow = (l15 & 3) * MSTRIDE;   // A-frag row for M=4 GEMMs (C rows 4..15 garbage)

    // mask stride sniff, parallel OR (no serial dependent-load chain)
    int orv = 0;
#pragma unroll
    for (int i = 1; i < 64; i += 2) orv |= nmask[i];
    const bool m64 = (orv == 0);

    if (tid < 128) {              // R rows: concat(node, time) for b=0..3
        const int b = tid >> 5, s = tid & 31;
        if (s < 16) ld8f(node  + (size_t)(gb0 + b) * 128 + s * 8,        &Rb[b * MSTRIDE + s * 8]);
        else        ld8f(timef + (size_t)(gb0 + b) * 128 + (s - 16) * 8, &Rb[b * MSTRIDE + s * 8]);
    } else if (tid < 256) {       // neighbor masks for b=0..3
        const int t = tid - 128, b = t >> 5, n = t & 31;
        const size_t j = (size_t)(gb0 + b) * 32 + n;
        mk[b][n] = m64 ? nmask[2 * j] : nmask[j];
    }
    // ---- stage X = concat(nbr_node, edge, nbr_time) bf16 [128][384], once ----
#pragma unroll
    for (int i = 0; i < 12; i++) {
        const int g  = i * 512 + tid;        // 0..6143
        const int r  = g / 48, c8 = g % 48;  // row 0..127, 8-elem chunk 0..47
        const float* base; int koff;
        if (c8 < 16)      { base = nbrnode; koff = c8 * 8; }
        else if (c8 < 32) { base = edge;    koff = (c8 - 16) * 8; }
        else              { base = nbrtime; koff = (c8 - 32) * 8; }
        ld8f(base + (size_t)(gb0 * 32 + r) * 128 + koff, &Xs[r * XSTRIDE + c8 * 8]);
    }
    __syncthreads();   // barrier #1: Rb/Xs/mk visible to all waves

    // wave w reads rows [32w, 32w+32) of each weight block
    const unsigned short* wq  = g_WQT  + (size_t)(w * 32 + l15) * 256 + quad * 8;
    const unsigned short* wkv = g_WKVT + (size_t)(w * 32 + l15) * 384 + quad * 8;
    const unsigned short* wo  = g_WOT  + (size_t)(w * 32 + l15) * 256 + quad * 8;
    const f32x4 zero4 = {0.0f, 0.0f, 0.0f, 0.0f};

    // ================= Phase Q: Q = R @ W_Q  (M=4, cols 32w..32w+32) ====================
    f32x4 accq[2];
#pragma unroll
    for (int ct = 0; ct < 2; ct++) accq[ct] = zero4;
    {
        bf16x8 bq[2][2];
#pragma unroll
        for (int p = 0; p < 2; p++)
#pragma unroll
            for (int ct = 0; ct < 2; ct++)
                bq[p][ct] = *(const bf16x8*)(wq + (size_t)(ct * 16) * 256 + p * 32);
#pragma unroll
        for (int kc = 0; kc < 8; kc++) {
            const int s = kc & 1;
            const bf16x8 aq = *(const bf16x8*)(&Rb[arow + kc * 32 + quad * 8]);
#pragma unroll
            for (int ct = 0; ct < 2; ct++)
                accq[ct] = __builtin_amdgcn_mfma_f32_16x16x32_bf16(aq, bq[s][ct], accq[ct], 0, 0, 0);
            if (kc + 2 < 8) {
#pragma unroll
                for (int ct = 0; ct < 2; ct++)
                    bq[s][ct] = *(const bf16x8*)(wq + (size_t)(ct * 16) * 256 + (kc + 2) * 32);
            }
        }
    }

    // ================= K-pass: K = X @ W_KV[:, 32w:32w+32]  (128 x 32, K=384) ===========
    f32x4 accK[8][2];
#pragma unroll
    for (int rt = 0; rt < 8; rt++)
#pragma unroll
        for (int ct = 0; ct < 2; ct++) accK[rt][ct] = zero4;
    {
        bf16x8 bK[2][2];
#pragma unroll
        for (int p = 0; p < 2; p++)
#pragma unroll
            for (int ct = 0; ct < 2; ct++)
                bK[p][ct] = *(const bf16x8*)(wkv + (size_t)(ct * 16) * 384 + p * 32);
#pragma unroll
        for (int kc = 0; kc < 12; kc++) {
            const int s = kc & 1;
            bf16x8 af[8];
#pragma unroll
            for (int rt = 0; rt < 8; rt++)
                af[rt] = *(const bf16x8*)(&Xs[(rt * 16 + l15) * XSTRIDE + kc * 32 + quad * 8]);
            __builtin_amdgcn_s_setprio(1);
#pragma unroll
            for (int ct = 0; ct < 2; ct++)
#pragma unroll
                for (int rt = 0; rt < 8; rt++)
                    accK[rt][ct] = __builtin_amdgcn_mfma_f32_16x16x32_bf16(af[rt], bK[s][ct], accK[rt][ct], 0, 0, 0);
            __builtin_amdgcn_s_setprio(0);
            if (kc + 2 < 12) {
#pragma unroll
                for (int ct = 0; ct < 2; ct++)
                    bK[s][ct] = *(const bf16x8*)(wkv + (size_t)(ct * 16) * 384 + (kc + 2) * 32);
            }
        }
    }

    // ================= softmax: scores + masked softmax (C-layout) ======================
    // accK: lane holds K[row n = rt*16+quad*4+rg][col = 32w+ct*16+l15]; batch bb = rt>>1.
    float aw[4][2][4];
    const float scl = 0.17677669529663687f;   // 32^-0.5
#pragma unroll
    for (int bb = 0; bb < 4; bb++) {
        float qv[2];
#pragma unroll
        for (int ct = 0; ct < 2; ct++) qv[ct] = __shfl(accq[ct][bb], l15, 64);
        float sv[2][4];
#pragma unroll
        for (int rtl = 0; rtl < 2; rtl++) {
            const int rt = bb * 2 + rtl;
#pragma unroll
            for (int rg = 0; rg < 4; rg++)
                sv[rtl][rg] = accK[rt][0][rg] * qv[0] + accK[rt][1][rg] * qv[1];
        }
#pragma unroll
        for (int m = 1; m <= 8; m <<= 1)
#pragma unroll
            for (int rtl = 0; rtl < 2; rtl++)
#pragma unroll
                for (int rg = 0; rg < 4; rg++)
                    sv[rtl][rg] += __shfl_xor(sv[rtl][rg], m, 64);
        float mx = -3.0e38f;
#pragma unroll
        for (int rtl = 0; rtl < 2; rtl++)
#pragma unroll
            for (int rg = 0; rg < 4; rg++) {
                const int n = rtl * 16 + quad * 4 + rg;
                sv[rtl][rg] = (mk[bb][n] != 0) ? sv[rtl][rg] * scl : -1.0e10f;
                mx = fmaxf(mx, sv[rtl][rg]);
            }
        mx = fmaxf(mx, __shfl_xor(mx, 16, 64));
        mx = fmaxf(mx, __shfl_xor(mx, 32, 64));
        float sum = 0.0f;
#pragma unroll
        for (int rtl = 0; rtl < 2; rtl++)
#pragma unroll
            for (int rg = 0; rg < 4; rg++) {
                const float e = __expf(sv[rtl][rg] - mx);
                aw[bb][rtl][rg] = e;
                sum += e;
            }
        sum += __shfl_xor(sum, 16, 64);
        sum += __shfl_xor(sum, 32, 64);
        const float inv = 1.0f / sum;
#pragma unroll
        for (int rtl = 0; rtl < 2; rtl++)
#pragma unroll
            for (int rg = 0; rg < 4; rg++)
                aw[bb][rtl][rg] *= inv;
    }

    // ================= V-pass: V = X @ W_KV[:, 256+32w:...+32]  (128 x 32, K=384) =======
    f32x4 accV[8][2];
#pragma unroll
    for (int rt = 0; rt < 8; rt++)
#pragma unroll
        for (int ct = 0; ct < 2; ct++) accV[rt][ct] = zero4;
    {
        bf16x8 bV[2][2];
#pragma unroll
        for (int p = 0; p < 2; p++)
#pragma unroll
            for (int ct = 0; ct < 2; ct++)
                bV[p][ct] = *(const bf16x8*)(wkv + (size_t)(256 + ct * 16) * 384 + p * 32);
#pragma unroll
        for (int kc = 0; kc < 12; kc++) {
            const int s = kc & 1;
            bf16x8 af[8];
#pragma unroll
            for (int rt = 0; rt < 8; rt++)
                af[rt] = *(const bf16x8*)(&Xs[(rt * 16 + l15) * XSTRIDE + kc * 32 + quad * 8]);
            __builtin_amdgcn_s_setprio(1);
#pragma unroll
            for (int ct = 0; ct < 2; ct++)
#pragma unroll
                for (int rt = 0; rt < 8; rt++)
                    accV[rt][ct] = __builtin_amdgcn_mfma_f32_16x16x32_bf16(af[rt], bV[s][ct], accV[rt][ct], 0, 0, 0);
            __builtin_amdgcn_s_setprio(0);
            if (kc + 2 < 12) {
#pragma unroll
                for (int ct = 0; ct < 2; ct++)
                    bV[s][ct] = *(const bf16x8*)(wkv + (size_t)(256 + ct * 16) * 384 + (kc + 2) * 32);
            }
        }
    }

    // ================= PV: O = A @ V  (reduce over rows n -> quad shuffles) =============
#pragma unroll
    for (int bb = 0; bb < 4; bb++)
#pragma unroll
        for (int ct = 0; ct < 2; ct++) {
            float o = 0.0f;
#pragma unroll
            for (int rtl = 0; rtl < 2; rtl++)
#pragma unroll
                for (int rg = 0; rg < 4; rg++)
                    o += aw[bb][rtl][rg] * accV[bb * 2 + rtl][ct][rg];
            o += __shfl_xor(o, 16, 64);
            o += __shfl_xor(o, 32, 64);
            if (quad == 0) {
                const int col = w * 32 + ct * 16 + l15;
                Ob[bb * MSTRIDE + col] = f2b(o);
            }
        }
    __syncthreads();   // barrier #2: all waves' O columns visible (V-pass done -> Xs dead)

    // ================= O-proj: out = O @ W_O + b_O + R, then LayerNorm ==================
    f32x4 acco[2];
#pragma unroll
    for (int ct = 0; ct < 2; ct++) acco[ct] = zero4;
    {
        bf16x8 bo[2][2];
#pragma unroll
        for (int p = 0; p < 2; p++)
#pragma unroll
            for (int ct = 0; ct < 2; ct++)
                bo[p][ct] = *(const bf16x8*)(wo + (size_t)(ct * 16) * 256 + p * 32);
#pragma unroll
        for (int kc = 0; kc < 8; kc++) {
            const int s = kc & 1;
            const bf16x8 ao = *(const bf16x8*)(&Ob[arow + kc * 32 + quad * 8]);
#pragma unroll
            for (int ct = 0; ct < 2; ct++)
                acco[ct] = __builtin_amdgcn_mfma_f32_16x16x32_bf16(ao, bo[s][ct], acco[ct], 0, 0, 0);
            if (kc + 2 < 8) {
#pragma unroll
                for (int ct = 0; ct < 2; ct++)
                    bo[s][ct] = *(const bf16x8*)(wo + (size_t)(ct * 16) * 256 + (kc + 2) * 32);
            }
        }
    }
    if (quad == 0) {
#pragma unroll
        for (int ct = 0; ct < 2; ct++) {
#pragma unroll
            for (int r = 0; r < 4; r++) {
                const int col = w * 32 + ct * 16 + l15;
                lnb[r * 256 + col] = acco[ct][r] + bO[col] + b2f(Rb[r * MSTRIDE + col]);
            }
        }
    }
    __syncthreads();   // barrier #3: lnb complete

    if (w < 4) {   // wave w -> batch row w
        const int bb = w;
        float x[4]; float s = 0.0f;
#pragma unroll
        for (int i = 0; i < 4; i++) { x[i] = lnb[bb * 256 + lane + i * 64]; s += x[i]; }
#pragma unroll
        for (int m = 1; m <= 32; m <<= 1) s += __shfl_xor(s, m, 64);
        const float mu = s * (1.0f / 256.0f);
        float s2 = 0.0f;
#pragma unroll
        for (int i = 0; i < 4; i++) { const float d = x[i] - mu; s2 += d * d; }
#pragma unroll
        for (int m = 1; m <= 32; m <<= 1) s2 += __shfl_xor(s2, m, 64);
        const float rstd = rsqrtf(s2 * (1.0f / 256.0f) + 1e-5f);
#pragma unroll
        for (int i = 0; i < 4; i++) {
            const int col = lane + i * 64;
            out[(size_t)(gb0 + bb) * 256 + col] =
                (x[i] - mu) * rstd * gam[col] + bet[col];
        }
    }
}

extern "C" void kernel_launch(void* const* d_in, const int* in_sizes, int n_in,
                              void* d_out, int out_size, void* d_ws, size_t ws_size,
                              hipStream_t stream) {
    const float* node    = (const float*)d_in[0];
    const float* timef   = (const float*)d_in[1];
    const float* edge    = (const float*)d_in[2];
    const float* nbrnode = (const float*)d_in[3];
    const float* nbrtime = (const float*)d_in[4];
    const int*   nmask   = (const int*)d_in[5];
    const float* W_Q     = (const float*)d_in[6];
    const float* W_KV    = (const float*)d_in[7];
    const float* W_O     = (const float*)d_in[8];
    const float* bO      = (const float*)d_in[9];
    const float* gam     = (const float*)d_in[10];
    const float* bet     = (const float*)d_in[11];

    unsigned short *wqt, *wkvt, *wot;
    hipGetSymbolAddress((void**)&wqt,  HIP_SYMBOL(g_WQT));
    hipGetSymbolAddress((void**)&wkvt, HIP_SYMBOL(g_WKVT));
    hipGetSymbolAddress((void**)&wot,  HIP_SYMBOL(g_WOT));

    transcvt_all<<<320, dim3(32, 8), 0, stream>>>(W_Q, W_KV, W_O, wqt, wkvt, wot);

    ta_fused<<<2048, 512, 0, stream>>>(node, timef, edge, nbrnode, nbrtime, nmask,
                                       bO, gam, bet, (float*)d_out);
}